// Round 3
// baseline (164.454 us; speedup 1.0000x reference)
//
#include <hip/hip_runtime.h>

// Problem: B=65536, C=2, P=41, L=4 cross-entropy + boundary weights + connectivity
constexpr int B   = 65536;
constexpr int P   = 41;
constexpr int L   = 4;
constexpr int PL  = P * L;          // 164 elems per (b,c)
constexpr int CPL = 2 * PL;         // 328 logits floats per batch

constexpr int NBATCH = 16;                   // batches per block
constexpr int NBLK   = B / NBATCH;           // 4096 blocks
constexpr int NLOG4  = NBATCH * (CPL / 4);   // 1312 float4 of logits per block
constexpr int NTGT4  = NBATCH * (PL  / 4);   // 656 int4 of targets per block
constexpr int NPAIR  = NBATCH * P;           // 656 (b,p) pairs per block

constexpr float INV_N = 1.0f / (float)(B * P * L);
constexpr float CW    = 0.001f;
// GAMMA = 1.0 -> alpha = 1.0, beta = 0.5

__global__ __launch_bounds__(256)
void lace_partial_kernel(const float4* __restrict__ lg4,
                         const int4*   __restrict__ tg4,
                         float*        __restrict__ partial)
{
    __shared__ float4 s_log[NLOG4];   // [lb*82 + c*41 + p]
    __shared__ int4   s_tgt[NTGT4];   // [lb*41 + p]
    __shared__ float  wsum[4];

    const int tid = threadIdx.x;
    const int b0  = blockIdx.x * NBATCH;

    // ---- stage: contiguous, fully coalesced, each HBM byte read once ----
    const float4* gsrc = lg4 + (size_t)b0 * (CPL / 4);
    const int4*   tsrc = tg4 + (size_t)b0 * (PL / 4);

    #pragma unroll
    for (int i = 0; i < 6; ++i) {            // 1312 = 5*256 + 32
        int idx = tid + i * 256;
        if (idx < NLOG4) s_log[idx] = gsrc[idx];
    }
    #pragma unroll
    for (int i = 0; i < 3; ++i) {            // 656 = 2*256 + 144
        int idx = tid + i * 256;
        if (idx < NTGT4) s_tgt[idx] = tsrc[idx];
    }
    __syncthreads();

    // ---- compute: 656 pairs, neighbors from LDS ----
    float sum = 0.0f;

    #pragma unroll
    for (int it = 0; it < 3; ++it) {
        int pid = tid + it * 256;
        if (pid < NPAIR) {
            int lb = pid / 41;               // compiler magic-mul
            int p  = pid - lb * 41;

            int lbase = lb * 82 + p;         // float4 idx, c=0
            int tbase = pid;                 // lb*41 + p == pid

            float4 a0 = s_log[lbase];        // logits[b,0,p,:]
            float4 a1 = s_log[lbase + 41];   // logits[b,1,p,:]
            int4   tc = s_tgt[tbase];

            bool hm1 = (p >= 1), hp1 = (p <= P - 2);
            bool hm2 = (p >= 2), hp2 = (p <= P - 3);

            float4 b0v = {0,0,0,0}, b1v = {0,0,0,0};
            int4 tm1 = {0,0,0,0}, tp1 = {0,0,0,0}, tm2 = {0,0,0,0}, tp2 = {0,0,0,0};
            if (hm1) { tm1 = s_tgt[tbase - 1]; b0v = s_log[lbase - 1]; b1v = s_log[lbase + 40]; }
            if (hp1) { tp1 = s_tgt[tbase + 1]; }
            if (hm2) { tm2 = s_tgt[tbase - 2]; }
            if (hp2) { tp2 = s_tgt[tbase + 2]; }

            const float* pa0 = (const float*)&a0;
            const float* pa1 = (const float*)&a1;
            const float* pb0 = (const float*)&b0v;
            const float* pb1 = (const float*)&b1v;
            const int* ptc  = (const int*)&tc;
            const int* ptm1 = (const int*)&tm1;
            const int* ptp1 = (const int*)&tp1;
            const int* ptm2 = (const int*)&tm2;
            const int* ptp2 = (const int*)&tp2;

            #pragma unroll
            for (int l = 0; l < 4; ++l) {
                float l0 = pa0[l], l1 = pa1[l];
                float mx  = fmaxf(l0, l1);
                float e   = __expf(-fabsf(l0 - l1));
                float lse = mx + __logf(1.0f + e);
                int   tg  = ptc[l];
                float lt  = tg ? l1 : l0;
                float loss = lse - lt;

                float w = 1.0f;
                if (hm1) w += fabsf((float)(tg - ptm1[l]));
                if (hp1) w += fabsf((float)(ptp1[l] - tg));
                if (hm2) w += 0.5f * fabsf((float)(tg - ptm2[l]));
                if (hp2) w += 0.5f * fabsf((float)(ptp2[l] - tg));

                float acc = loss * w;

                if (hm1) {
                    bool pred  = (l1 > l0);
                    bool predm = (pb1[l] > pb0[l]);
                    if (pred != predm) acc += CW;
                }
                sum += acc;
            }
        }
    }

    // ---- block reduction -> one partial per block ----
    #pragma unroll
    for (int off = 32; off > 0; off >>= 1)
        sum += __shfl_down(sum, off, 64);

    int lane = tid & 63;
    int wid  = tid >> 6;
    if (lane == 0) wsum[wid] = sum;
    __syncthreads();
    if (tid == 0)
        partial[blockIdx.x] = wsum[0] + wsum[1] + wsum[2] + wsum[3];
}

__global__ __launch_bounds__(1024)
void lace_reduce_kernel(const float* __restrict__ partial,
                        float*       __restrict__ out)
{
    // NBLK = 4096 = 4 * 1024 exactly
    float s = 0.0f;
    #pragma unroll
    for (int i = 0; i < 4; ++i)
        s += partial[threadIdx.x + i * 1024];

    #pragma unroll
    for (int off = 32; off > 0; off >>= 1)
        s += __shfl_down(s, off, 64);

    __shared__ float wsum[16];
    int lane = threadIdx.x & 63;
    int wid  = threadIdx.x >> 6;
    if (lane == 0) wsum[wid] = s;
    __syncthreads();
    if (threadIdx.x == 0) {
        float total = 0.0f;
        #pragma unroll
        for (int i = 0; i < 16; ++i) total += wsum[i];
        out[0] = total * INV_N;
    }
}

extern "C" void kernel_launch(void* const* d_in, const int* in_sizes, int n_in,
                              void* d_out, int out_size, void* d_ws, size_t ws_size,
                              hipStream_t stream) {
    const float4* lg4 = (const float4*)d_in[0];
    const int4*   tg4 = (const int4*)d_in[1];
    float* out     = (float*)d_out;
    float* partial = (float*)d_ws;   // 4096 floats

    lace_partial_kernel<<<NBLK, 256, 0, stream>>>(lg4, tg4, partial);
    lace_reduce_kernel<<<1, 1024, 0, stream>>>(partial, out);
}